// Round 4
// baseline (476.272 us; speedup 1.0000x reference)
//
#include <hip/hip_runtime.h>

// DEMA over x:(B=32, T=4096, F=512) fp32, scan along T.
// Chunked-with-halo parallelization: A = [[1-a,1-a],[-a*b,1-a*b]] has
// |lambda| = sqrt(0.7) ~ 0.8367 -> ||A^128|| ~ 1e-9, so a 128-step warmup
// from the cheap init (s=x[t-1], b=x[t]-x[t-1]) reproduces the state to
// ~1e-8. Chunks of T are independent given the halo -> fully parallel.
//
// Memory-latency attack (prior measured 469 us vs ~102 us BW floor):
//  - float4/thread: 16 B/lane loads, 4 independent scan chains (ILP).
//  - DOUBLE-BUFFERED depth-8 prefetch (bufA/bufB ping-pong, statically
//    indexed -> stays in VGPRs): each buffer's 8 loads are issued two
//    group-computes ahead of consumption, so the compiler emits counted
//    s_waitcnt (not vmcnt(0) drains) and up to 16 KB/wave stays in flight.
//  - Worst case (full drain per group) still leaves 8 KB/wave in flight
//    -> ~25 B/cyc/CU vs 10.2 needed -> BW-bound either way.

#define DEMA_ALPHA 0.3f
#define DEMA_BETA  0.1f
#define DEMA_T     4096
#define DEMA_B     32
#define DEMA_F     512
#define DEMA_F4    (DEMA_F / 4)      // 128 float4 per (b,t) row
#define DEMA_L     256               // output chunk length
#define DEMA_H     128               // warmup halo length
#define DEMA_C     (DEMA_T / DEMA_L) // 16 chunks
#define PRE_D      8                 // prefetch group size (float4 loads)

__device__ __forceinline__ void dema_step(float4& s, float4& bb, const float4 xt) {
    const float a  = DEMA_ALPHA;
    const float a1 = 1.0f - DEMA_ALPHA;  // 0.7
    const float be = DEMA_BETA;
    const float b1 = 1.0f - DEMA_BETA;   // 0.9
    float4 sp = s;
    s.x = a * xt.x + a1 * (sp.x + bb.x);
    s.y = a * xt.y + a1 * (sp.y + bb.y);
    s.z = a * xt.z + a1 * (sp.z + bb.z);
    s.w = a * xt.w + a1 * (sp.w + bb.w);
    bb.x = be * (s.x - sp.x) + b1 * bb.x;
    bb.y = be * (s.y - sp.y) + b1 * bb.y;
    bb.z = be * (s.z - sp.z) + b1 * bb.z;
    bb.w = be * (s.w - sp.w) + b1 * bb.w;
}

__device__ __forceinline__ void load_group(float4 (&buf)[PRE_D],
                                           const float4* __restrict__ p, int ti) {
    #pragma unroll
    for (int j = 0; j < PRE_D; ++j) buf[j] = p[(ti + j) * DEMA_F4];
}

template <bool STORE>
__device__ __forceinline__ void compute_group(const float4 (&buf)[PRE_D],
                                              float4& s, float4& bb,
                                              float4* __restrict__ op, int ti) {
    #pragma unroll
    for (int j = 0; j < PRE_D; ++j) {
        dema_step(s, bb, buf[j]);
        if (STORE) op[(ti + j) * DEMA_F4] = s;
    }
}

__global__ __launch_bounds__(128) void dema_kernel(const float* __restrict__ x,
                                                   float* __restrict__ out) {
    const int f4 = threadIdx.x;        // 0..127, coalesced float4 across f
    const int b  = blockIdx.x;         // 0..31
    const int c  = blockIdx.y;         // 0..15 chunk idx

    const float4* __restrict__ xp =
        reinterpret_cast<const float4*>(x) + (size_t)b * DEMA_T * DEMA_F4 + f4;
    float4* __restrict__ op =
        reinterpret_cast<float4*>(out) + (size_t)b * DEMA_T * DEMA_F4 + f4;

    float4 bufA[PRE_D], bufB[PRE_D];   // ping-pong prefetch buffers
    float4 s, bb;

    if (c == 0) {
        // Exact prefix, steps 0..255, all stored.
        load_group(bufA, xp, 0);
        load_group(bufB, xp, PRE_D);
        s = bufA[0];
        bb.x = bufA[1].x - s.x;
        bb.y = bufA[1].y - s.y;
        bb.z = bufA[1].z - s.z;
        bb.w = bufA[1].w - s.w;
        op[0] = s;
        #pragma unroll
        for (int j = 1; j < PRE_D; ++j) {   // steps 1..7
            dema_step(s, bb, bufA[j]);
            op[j * DEMA_F4] = s;
        }
        load_group(bufA, xp, 2 * PRE_D);    // group @16
        compute_group<true>(bufB, s, bb, op, PRE_D);   // steps 8..15
        load_group(bufB, xp, 3 * PRE_D);    // group @24
        #pragma unroll 1
        for (int ii = 2 * PRE_D; ii < DEMA_L; ii += 2 * PRE_D) {
            compute_group<true>(bufA, s, bb, op, ii);
            if (ii + 2 * PRE_D < DEMA_L) load_group(bufA, xp, ii + 2 * PRE_D);
            compute_group<true>(bufB, s, bb, op, ii + PRE_D);
            if (ii + 3 * PRE_D < DEMA_L) load_group(bufB, xp, ii + 3 * PRE_D);
        }
    } else {
        const int t0 = c * DEMA_L;     // >= 256
        const int tw = t0 - DEMA_H;    // >= 128
        const float4* __restrict__ xw = xp + (size_t)tw * DEMA_F4;
        float4* __restrict__ ow = op + (size_t)tw * DEMA_F4;
        const int NT = DEMA_H + DEMA_L;  // 384 relative steps

        load_group(bufA, xw, 0);
        load_group(bufB, xw, PRE_D);
        s = xw[-DEMA_F4];              // x_{tw-1} (approx state init)
        bb.x = bufA[0].x - s.x;        // x_tw - x_{tw-1}
        bb.y = bufA[0].y - s.y;
        bb.z = bufA[0].z - s.z;
        bb.w = bufA[0].w - s.w;

        // Warmup: relative steps 0..127, no stores. All prefetches in range
        // (max load index 112+24+7 = 143 < 384).
        #pragma unroll 1
        for (int ii = 0; ii < DEMA_H; ii += 2 * PRE_D) {
            compute_group<false>(bufA, s, bb, ow, ii);
            load_group(bufA, xw, ii + 2 * PRE_D);
            compute_group<false>(bufB, s, bb, ow, ii + PRE_D);
            load_group(bufB, xw, ii + 3 * PRE_D);
        }
        // Output: relative steps 128..383 (absolute t0..t0+255).
        #pragma unroll 1
        for (int ii = DEMA_H; ii < NT; ii += 2 * PRE_D) {
            compute_group<true>(bufA, s, bb, ow, ii);
            if (ii + 2 * PRE_D < NT) load_group(bufA, xw, ii + 2 * PRE_D);
            compute_group<true>(bufB, s, bb, ow, ii + PRE_D);
            if (ii + 3 * PRE_D < NT) load_group(bufB, xw, ii + 3 * PRE_D);
        }
    }
}

extern "C" void kernel_launch(void* const* d_in, const int* in_sizes, int n_in,
                              void* d_out, int out_size, void* d_ws, size_t ws_size,
                              hipStream_t stream) {
    const float* x = (const float*)d_in[0];
    float* out = (float*)d_out;

    dim3 block(128, 1, 1);
    dim3 grid(DEMA_B, DEMA_C, 1);      // 32 x 16 = 512 blocks, 1024 waves
    dema_kernel<<<grid, block, 0, stream>>>(x, out);
}

// Round 5
// 470.477 us; speedup vs baseline: 1.0123x; 1.0123x over previous
//
#include <hip/hip_runtime.h>

// DEMA over x:(B=32, T=4096, F=512) fp32, scan along T.
// Chunked-with-halo parallelization: A = [[1-a,1-a],[-a*b,1-a*b]] has
// |lambda| = sqrt(0.7) ~ 0.8367 -> ||A^128|| ~ 1e-9, so a 128-step warmup
// from the cheap init (s=x[t-1], b=x[t]-x[t-1]) reproduces the state to
// ~1e-8. Chunks of T are independent given the halo -> fully parallel.
//
// Round-4 post-mortem: VGPR_Count=52 proved the compiler (targeting 8
// waves/SIMD under plain __launch_bounds__(128)) DISCARDED the ping-pong
// buffers and kept ~1 load in flight/wave. 1024 waves x 1 KB = 1 MB in
// flight @ ~1000cyc latency -> 2.6 TB/s, exactly as measured (178 us).
// Fix: __launch_bounds__(128, 1) opens the VGPR budget (we only run
// 1 wave/SIMD anyway) + QUAD-buffered depth-8 prefetch (4 named float4[8]
// buffers, statically indexed): loads issue 3 compute-groups (~1300 cyc)
// ahead of use, up to 32 KB/wave in flight -> BW-bound with margin.
// Secondary: nontemporal stores keep the 256 MiB output from evicting the
// input halo in L2/L3 (FETCH was 188 MiB < input size thanks to L3).

#define DEMA_ALPHA 0.3f
#define DEMA_BETA  0.1f
#define DEMA_T     4096
#define DEMA_B     32
#define DEMA_F     512
#define DEMA_F4    (DEMA_F / 4)      // 128 float4 per (b,t) row
#define DEMA_L     256               // output chunk length
#define DEMA_H     128               // warmup halo length
#define DEMA_C     (DEMA_T / DEMA_L) // 16 chunks
#define PRE_D      8                 // prefetch group size (float4 loads)

typedef float v4f __attribute__((ext_vector_type(4)));

__device__ __forceinline__ void store_nt(float4* p, const float4 v) {
    v4f t;
    t.x = v.x; t.y = v.y; t.z = v.z; t.w = v.w;
    __builtin_nontemporal_store(t, reinterpret_cast<v4f*>(p));
}

__device__ __forceinline__ void dema_step(float4& s, float4& bb, const float4 xt) {
    const float a  = DEMA_ALPHA;
    const float a1 = 1.0f - DEMA_ALPHA;  // 0.7
    const float be = DEMA_BETA;
    const float b1 = 1.0f - DEMA_BETA;   // 0.9
    float4 sp = s;
    s.x = a * xt.x + a1 * (sp.x + bb.x);
    s.y = a * xt.y + a1 * (sp.y + bb.y);
    s.z = a * xt.z + a1 * (sp.z + bb.z);
    s.w = a * xt.w + a1 * (sp.w + bb.w);
    bb.x = be * (s.x - sp.x) + b1 * bb.x;
    bb.y = be * (s.y - sp.y) + b1 * bb.y;
    bb.z = be * (s.z - sp.z) + b1 * bb.z;
    bb.w = be * (s.w - sp.w) + b1 * bb.w;
}

__device__ __forceinline__ void load_group(float4 (&buf)[PRE_D],
                                           const float4* __restrict__ p, int ti) {
    #pragma unroll
    for (int j = 0; j < PRE_D; ++j) buf[j] = p[(ti + j) * DEMA_F4];
}

template <bool STORE>
__device__ __forceinline__ void compute_group(const float4 (&buf)[PRE_D],
                                              float4& s, float4& bb,
                                              float4* __restrict__ op, int ti) {
    #pragma unroll
    for (int j = 0; j < PRE_D; ++j) {
        dema_step(s, bb, buf[j]);
        if (STORE) store_nt(&op[(ti + j) * DEMA_F4], s);
    }
}

__global__ __launch_bounds__(128, 1) void dema_kernel(const float* __restrict__ x,
                                                      float* __restrict__ out) {
    const int f4 = threadIdx.x;        // 0..127, coalesced float4 across f
    const int b  = blockIdx.x;         // 0..31
    const int c  = blockIdx.y;         // 0..15 chunk idx

    const float4* __restrict__ xp =
        reinterpret_cast<const float4*>(x) + (size_t)b * DEMA_T * DEMA_F4 + f4;
    float4* __restrict__ op =
        reinterpret_cast<float4*>(out) + (size_t)b * DEMA_T * DEMA_F4 + f4;

    // Quad-rotation prefetch buffers: buffer k holds group g with g%4==k,
    // loaded while group g-4..g-1 compute. All names static -> VGPRs.
    float4 b0[PRE_D], b1[PRE_D], b2[PRE_D], b3[PRE_D];
    float4 s, bb;

    if (c == 0) {
        // Exact prefix, steps 0..255, all stored. NG = 32 groups.
        load_group(b0, xp, 0);
        load_group(b1, xp, PRE_D);
        load_group(b2, xp, 2 * PRE_D);
        load_group(b3, xp, 3 * PRE_D);
        s = b0[0];
        bb.x = b0[1].x - s.x;          // b_0 = x_1 - x_0
        bb.y = b0[1].y - s.y;
        bb.z = b0[1].z - s.z;
        bb.w = b0[1].w - s.w;
        store_nt(&op[0], s);
        #pragma unroll
        for (int j = 1; j < PRE_D; ++j) {   // steps 1..7 (group 0, special)
            dema_step(s, bb, b0[j]);
            store_nt(&op[j * DEMA_F4], s);
        }
        load_group(b0, xp, 4 * PRE_D);
        compute_group<true>(b1, s, bb, op, PRE_D);
        load_group(b1, xp, 5 * PRE_D);
        compute_group<true>(b2, s, bb, op, 2 * PRE_D);
        load_group(b2, xp, 6 * PRE_D);
        compute_group<true>(b3, s, bb, op, 3 * PRE_D);
        load_group(b3, xp, 7 * PRE_D);
        #pragma unroll 1
        for (int ii = 4 * PRE_D; ii < DEMA_L; ii += 4 * PRE_D) {
            compute_group<true>(b0, s, bb, op, ii);
            if (ii + 4 * PRE_D < DEMA_L) load_group(b0, xp, ii + 4 * PRE_D);
            compute_group<true>(b1, s, bb, op, ii + PRE_D);
            if (ii + 5 * PRE_D < DEMA_L) load_group(b1, xp, ii + 5 * PRE_D);
            compute_group<true>(b2, s, bb, op, ii + 2 * PRE_D);
            if (ii + 6 * PRE_D < DEMA_L) load_group(b2, xp, ii + 6 * PRE_D);
            compute_group<true>(b3, s, bb, op, ii + 3 * PRE_D);
            if (ii + 7 * PRE_D < DEMA_L) load_group(b3, xp, ii + 7 * PRE_D);
        }
    } else {
        const int t0 = c * DEMA_L;     // >= 256
        const int tw = t0 - DEMA_H;    // >= 128
        const float4* __restrict__ xw = xp + (size_t)tw * DEMA_F4;
        float4* __restrict__ ow = op + (size_t)tw * DEMA_F4;
        const int NT = DEMA_H + DEMA_L;  // 384 relative steps, NG = 48 groups

        load_group(b0, xw, 0);
        load_group(b1, xw, PRE_D);
        load_group(b2, xw, 2 * PRE_D);
        load_group(b3, xw, 3 * PRE_D);
        s = xw[-DEMA_F4];              // x_{tw-1} (approx state init)
        bb.x = b0[0].x - s.x;          // x_tw - x_{tw-1}
        bb.y = b0[0].y - s.y;
        bb.z = b0[0].z - s.z;
        bb.w = b0[0].w - s.w;

        // Warmup: relative steps 0..127 (16 groups), no stores. Loads reach
        // at most rel 159 < 384 -> unguarded.
        #pragma unroll 1
        for (int ii = 0; ii < DEMA_H; ii += 4 * PRE_D) {
            compute_group<false>(b0, s, bb, ow, ii);
            load_group(b0, xw, ii + 4 * PRE_D);
            compute_group<false>(b1, s, bb, ow, ii + PRE_D);
            load_group(b1, xw, ii + 5 * PRE_D);
            compute_group<false>(b2, s, bb, ow, ii + 2 * PRE_D);
            load_group(b2, xw, ii + 6 * PRE_D);
            compute_group<false>(b3, s, bb, ow, ii + 3 * PRE_D);
            load_group(b3, xw, ii + 7 * PRE_D);
        }
        // Output: relative steps 128..383 (absolute t0..t0+255).
        #pragma unroll 1
        for (int ii = DEMA_H; ii < NT; ii += 4 * PRE_D) {
            compute_group<true>(b0, s, bb, ow, ii);
            if (ii + 4 * PRE_D < NT) load_group(b0, xw, ii + 4 * PRE_D);
            compute_group<true>(b1, s, bb, ow, ii + PRE_D);
            if (ii + 5 * PRE_D < NT) load_group(b1, xw, ii + 5 * PRE_D);
            compute_group<true>(b2, s, bb, ow, ii + 2 * PRE_D);
            if (ii + 6 * PRE_D < NT) load_group(b2, xw, ii + 6 * PRE_D);
            compute_group<true>(b3, s, bb, ow, ii + 3 * PRE_D);
            if (ii + 7 * PRE_D < NT) load_group(b3, xw, ii + 7 * PRE_D);
        }
    }
}

extern "C" void kernel_launch(void* const* d_in, const int* in_sizes, int n_in,
                              void* d_out, int out_size, void* d_ws, size_t ws_size,
                              hipStream_t stream) {
    const float* x = (const float*)d_in[0];
    float* out = (float*)d_out;

    dim3 block(128, 1, 1);
    dim3 grid(DEMA_B, DEMA_C, 1);      // 32 x 16 = 512 blocks, 1024 waves
    dema_kernel<<<grid, block, 0, stream>>>(x, out);
}